// Round 1
// 119.205 us; speedup vs baseline: 1.0174x; 1.0174x over previous
//
#include <hip/hip_runtime.h>
#include <math.h>

#define GRID_N 7
#define NB 2
#define NC 20
#define IS 8            // NB*4
#define DCH 30          // NB*5 + NC
#define BATCH 8192
#define NCELL (BATCH * GRID_N * GRID_N)   // 401408
#define INV_GRID (1.0f / 7.0f)
#define INV_BATCH (1.0f / 8192.0f)

#define CELLS_PER_BLOCK 256
#define F4_PER_BLOCK (CELLS_PER_BLOCK * DCH / 4)   // 1920 float4 per buffer

__device__ __forceinline__ float bce(float l, float t) {
    // max(l,0) - l*t + log1p(exp(-|l|))
    return fmaxf(l, 0.0f) - l * t + logf(1.0f + expf(-fabsf(l)));
}

__device__ __forceinline__ float box_loss(const float* pb, const float* gb) {
    float dx = pb[0] - gb[0];
    float dy = pb[1] - gb[1];
    float dw = sqrtf(fabsf(pb[2])) - sqrtf(gb[2]);   // ref: sqrt(|pw|), sqrt(gw) no abs
    float dh = sqrtf(fabsf(pb[3])) - sqrtf(gb[3]);
    return dx * dx + dy * dy + dw * dw + dh * dh;
}

// Coalesced global->LDS direct copy, 16B per lane.
// LDS dest is wave-uniform base + lane*16 (linear layout matches exactly).
__device__ __forceinline__ void load_lds16(const float4* gptr, float4* lptr) {
    __builtin_amdgcn_global_load_lds(
        (const __attribute__((address_space(1))) void*)(gptr),
        (__attribute__((address_space(3))) void*)(lptr),
        16, 0, 0);
}

__global__ __launch_bounds__(256) void yolo_loss_kernel(
        const float* __restrict__ p, const float* __restrict__ g,
        float* __restrict__ out) {
    __shared__ float sp[CELLS_PER_BLOCK * DCH];   // 30720 B
    __shared__ float sg[CELLS_PER_BLOCK * DCH];   // 30720 B
    __shared__ float ws_red[4];

    const int tid = threadIdx.x;
    const long blockCell = (long)blockIdx.x * CELLS_PER_BLOCK;

    // ---- stage p-tile and g-tile into LDS, perfectly coalesced 16B/lane ----
    const float4* pB = reinterpret_cast<const float4*>(p + blockCell * DCH);
    const float4* gB = reinterpret_cast<const float4*>(g + blockCell * DCH);
    float4* sp4 = reinterpret_cast<float4*>(sp);
    float4* sg4 = reinterpret_cast<float4*>(sg);

    #pragma unroll
    for (int k = 0; k < 7; ++k) {               // 7*256 = 1792 float4
        load_lds16(pB + k * 256 + tid, sp4 + k * 256 + tid);
        load_lds16(gB + k * 256 + tid, sg4 + k * 256 + tid);
    }
    if (tid < F4_PER_BLOCK - 7 * 256) {         // tail 128 float4 (waves 0,1 — uniform)
        load_lds16(pB + 7 * 256 + tid, sp4 + 7 * 256 + tid);
        load_lds16(gB + 7 * 256 + tid, sg4 + 7 * 256 + tid);
    }
    __syncthreads();   // compiler emits vmcnt(0) drain before barrier

    // ---- per-cell compute, reading from LDS (stride 30 -> 2-way bank alias, free) ----
    const float* pv = sp + tid * DCH;
    const float* gv = sg + tid * DCH;

    const int cell = (int)blockCell + tid;
    const int ij = cell % (GRID_N * GRID_N);
    const float fi = (float)(ij / GRID_N);   // row
    const float fj = (float)(ij % GRID_N);   // col  (cr = [col, row])

    float acc = 0.0f;
    const float conf_g = gv[IS];

    if (conf_g == 0.0f) {
        // negative cells: 0.5 * sum BCE(conf logits, 0)
        acc = 0.5f * (bce(pv[IS], 0.0f) + bce(pv[IS + 1], 0.0f));
    } else if (conf_g > 0.0f) {
        // ---- class loss ----
        float cls = 0.0f;
        #pragma unroll
        for (int c = 0; c < NC; ++c) cls += bce(pv[NB * 5 + c], gv[NB * 5 + c]);

        // ---- poff = [sigmoid(xy), wh] ----
        float po[NB][4];
        #pragma unroll
        for (int k = 0; k < NB; ++k) {
            po[k][0] = 1.0f / (1.0f + expf(-pv[4*k + 0]));
            po[k][1] = 1.0f / (1.0f + expf(-pv[4*k + 1]));
            po[k][2] = pv[4*k + 2];
            po[k][3] = pv[4*k + 3];
        }

        // ---- ltrb for pred and gt ----
        float pl[NB][4], gl[NB][4], pa[NB], ga[NB];
        float gbx[NB][4];
        #pragma unroll
        for (int m = 0; m < NB; ++m) {
            gbx[m][0] = gv[4*m + 0]; gbx[m][1] = gv[4*m + 1];
            gbx[m][2] = gv[4*m + 2]; gbx[m][3] = gv[4*m + 3];
        }
        #pragma unroll
        for (int k = 0; k < NB; ++k) {
            float cx = (po[k][0] + fj) * INV_GRID;
            float cy = (po[k][1] + fi) * INV_GRID;
            float w = po[k][2], h = po[k][3];
            pl[k][0] = cx - w * 0.5f; pl[k][1] = cy - h * 0.5f;
            pl[k][2] = cx + w * 0.5f; pl[k][3] = cy + h * 0.5f;
            pa[k] = (pl[k][2] - pl[k][0]) * (pl[k][3] - pl[k][1]);   // ref computes area from ltrb
        }
        #pragma unroll
        for (int m = 0; m < NB; ++m) {
            float cx = (gbx[m][0] + fj) * INV_GRID;
            float cy = (gbx[m][1] + fi) * INV_GRID;
            float w = gbx[m][2], h = gbx[m][3];
            gl[m][0] = cx - w * 0.5f; gl[m][1] = cy - h * 0.5f;
            gl[m][2] = cx + w * 0.5f; gl[m][3] = cy + h * 0.5f;
            ga[m] = (gl[m][2] - gl[m][0]) * (gl[m][3] - gl[m][1]);
        }

        // ---- iou(pred k, gt m) and argmax over k (first-max on ties) ----
        int ind[NB];
        #pragma unroll
        for (int m = 0; m < NB; ++m) {
            float iou_km[NB];
            #pragma unroll
            for (int k = 0; k < NB; ++k) {
                float ltx = fmaxf(pl[k][0], gl[m][0]);
                float lty = fmaxf(pl[k][1], gl[m][1]);
                float rbx = fminf(pl[k][2], gl[m][2]);
                float rby = fminf(pl[k][3], gl[m][3]);
                float w = fmaxf(rbx - ltx, 0.0f);
                float h = fmaxf(rby - lty, 0.0f);
                float inter = w * h;
                iou_km[k] = inter / (pa[k] + ga[m] - inter + 1e-7f);
            }
            ind[m] = (iou_km[1] > iou_km[0]) ? 1 : 0;   // jnp.argmax: first max wins
        }

        // gathered[m] = poff[ind[m]]  (size-2 select, keep in registers)
        float gth0[4], gth1[4];
        #pragma unroll
        for (int c = 0; c < 4; ++c) {
            gth0[c] = ind[0] ? po[1][c] : po[0][c];
            gth1[c] = ind[1] ? po[1][c] : po[0][c];
        }

        // same_g: exact elementwise equality of the two gt boxes
        bool same_g = (gbx[0][0] == gbx[1][0]) && (gbx[0][1] == gbx[1][1]) &&
                      (gbx[0][2] == gbx[1][2]) && (gbx[0][3] == gbx[1][3]);
        bool same_ind = (ind[0] == ind[1]);

        float lossA = box_loss(gth0, gbx[0]);
        float lossB = box_loss(po[0], gbx[0]) + box_loss(po[1], gbx[1]);
        float lossC = box_loss(gth0, gbx[0]) + box_loss(gth1, gbx[1]);
        float box_cell = same_g ? lossA : (same_ind ? lossB : lossC);

        float pc0 = pv[IS], pc1 = pv[IS + 1];
        float confA = bce(ind[1] ? pc1 : pc0, 1.0f);
        float confBC = bce(pc0, 1.0f) + bce(pc1, 1.0f);
        float conf_cell = same_g ? confA : confBC;

        acc = 5.0f * box_cell + conf_cell + cls;
    }
    // conf_g < 0: contributes nothing (matches reference masks)

    // ---- block reduction: wave shuffle -> LDS -> one atomic per block ----
    #pragma unroll
    for (int off = 32; off > 0; off >>= 1) acc += __shfl_down(acc, off, 64);

    const int lane = threadIdx.x & 63;
    const int wid = threadIdx.x >> 6;
    if (lane == 0) ws_red[wid] = acc;
    __syncthreads();
    if (threadIdx.x == 0) {
        float s = ws_red[0] + ws_red[1] + ws_red[2] + ws_red[3];
        atomicAdd(out, s * INV_BATCH);
    }
}

extern "C" void kernel_launch(void* const* d_in, const int* in_sizes, int n_in,
                              void* d_out, int out_size, void* d_ws, size_t ws_size,
                              hipStream_t stream) {
    const float* p = (const float*)d_in[0];
    const float* g = (const float*)d_in[1];
    float* out = (float*)d_out;

    hipMemsetAsync(out, 0, sizeof(float), stream);   // d_out is poisoned 0xAA each call

    const int block = 256;
    const int grid = NCELL / CELLS_PER_BLOCK;        // 1568 blocks
    yolo_loss_kernel<<<grid, block, 0, stream>>>(p, g, out);
}

// Round 2
// 119.075 us; speedup vs baseline: 1.0185x; 1.0011x over previous
//
#include <hip/hip_runtime.h>
#include <math.h>

#define GRID_N 7
#define NB 2
#define NC 20
#define IS 8            // NB*4
#define DCH 30          // NB*5 + NC
#define BATCH 8192
#define NCELL (BATCH * GRID_N * GRID_N)   // 401408
#define INV_GRID (1.0f / 7.0f)
#define INV_BATCH (1.0f / 8192.0f)

#define CPB 128                               // cells per block (= block threads)
#define NBLOCKS (NCELL / CPB)                 // 3136
#define F4_PER_BUF (CPB * DCH / 4)            // 960 float4 per buffer

__device__ __forceinline__ float bce(float l, float t) {
    // max(l,0) - l*t + log1p(exp(-|l|))
    return fmaxf(l, 0.0f) - l * t + logf(1.0f + expf(-fabsf(l)));
}

__device__ __forceinline__ float box_loss(const float* pb, const float* gb) {
    float dx = pb[0] - gb[0];
    float dy = pb[1] - gb[1];
    float dw = sqrtf(fabsf(pb[2])) - sqrtf(gb[2]);   // ref: sqrt(|pw|), sqrt(gw) no abs
    float dh = sqrtf(fabsf(pb[3])) - sqrtf(gb[3]);
    return dx * dx + dy * dy + dw * dw + dh * dh;
}

// Coalesced global->LDS direct copy, 16B per lane.
// LDS dest is wave-uniform base + lane*16 (linear layout matches exactly).
__device__ __forceinline__ void load_lds16(const float4* gptr, float4* lptr) {
    __builtin_amdgcn_global_load_lds(
        (const __attribute__((address_space(1))) void*)(gptr),
        (__attribute__((address_space(3))) void*)(lptr),
        16, 0, 0);
}

template <bool USE_ATOMIC>
__global__ __launch_bounds__(CPB) void yolo_loss_kernel(
        const float* __restrict__ p, const float* __restrict__ g,
        float* __restrict__ partial_or_out) {
    __shared__ float sp[CPB * DCH];   // 15360 B
    __shared__ float sg[CPB * DCH];   // 15360 B
    __shared__ float ws_red[CPB / 64];

    const int tid = threadIdx.x;
    const long blockCell = (long)blockIdx.x * CPB;

    // ---- stage p-tile and g-tile into LDS, perfectly coalesced 16B/lane ----
    const float4* pB = reinterpret_cast<const float4*>(p + blockCell * DCH);
    const float4* gB = reinterpret_cast<const float4*>(g + blockCell * DCH);
    float4* sp4 = reinterpret_cast<float4*>(sp);
    float4* sg4 = reinterpret_cast<float4*>(sg);

    #pragma unroll
    for (int k = 0; k < 7; ++k) {               // 7*128 = 896 float4
        load_lds16(pB + k * CPB + tid, sp4 + k * CPB + tid);
        load_lds16(gB + k * CPB + tid, sg4 + k * CPB + tid);
    }
    if (tid < F4_PER_BUF - 7 * CPB) {           // tail 64 float4 (wave 0, uniform)
        load_lds16(pB + 7 * CPB + tid, sp4 + 7 * CPB + tid);
        load_lds16(gB + 7 * CPB + tid, sg4 + 7 * CPB + tid);
    }
    __syncthreads();   // compiler emits vmcnt(0) drain before barrier

    // ---- per-cell compute, reading from LDS (stride 30 -> 2-way bank alias, free) ----
    const float* pv = sp + tid * DCH;
    const float* gv = sg + tid * DCH;

    const int cell = (int)blockCell + tid;
    const int ij = cell % (GRID_N * GRID_N);
    const float fi = (float)(ij / GRID_N);   // row
    const float fj = (float)(ij % GRID_N);   // col  (cr = [col, row])

    float acc = 0.0f;
    const float conf_g = gv[IS];

    if (conf_g == 0.0f) {
        // negative cells: 0.5 * sum BCE(conf logits, 0)
        acc = 0.5f * (bce(pv[IS], 0.0f) + bce(pv[IS + 1], 0.0f));
    } else if (conf_g > 0.0f) {
        // ---- class loss ----
        float cls = 0.0f;
        #pragma unroll
        for (int c = 0; c < NC; ++c) cls += bce(pv[NB * 5 + c], gv[NB * 5 + c]);

        // ---- poff = [sigmoid(xy), wh] ----
        float po[NB][4];
        #pragma unroll
        for (int k = 0; k < NB; ++k) {
            po[k][0] = 1.0f / (1.0f + expf(-pv[4*k + 0]));
            po[k][1] = 1.0f / (1.0f + expf(-pv[4*k + 1]));
            po[k][2] = pv[4*k + 2];
            po[k][3] = pv[4*k + 3];
        }

        // ---- ltrb for pred and gt ----
        float pl[NB][4], gl[NB][4], pa[NB], ga[NB];
        float gbx[NB][4];
        #pragma unroll
        for (int m = 0; m < NB; ++m) {
            gbx[m][0] = gv[4*m + 0]; gbx[m][1] = gv[4*m + 1];
            gbx[m][2] = gv[4*m + 2]; gbx[m][3] = gv[4*m + 3];
        }
        #pragma unroll
        for (int k = 0; k < NB; ++k) {
            float cx = (po[k][0] + fj) * INV_GRID;
            float cy = (po[k][1] + fi) * INV_GRID;
            float w = po[k][2], h = po[k][3];
            pl[k][0] = cx - w * 0.5f; pl[k][1] = cy - h * 0.5f;
            pl[k][2] = cx + w * 0.5f; pl[k][3] = cy + h * 0.5f;
            pa[k] = (pl[k][2] - pl[k][0]) * (pl[k][3] - pl[k][1]);   // ref computes area from ltrb
        }
        #pragma unroll
        for (int m = 0; m < NB; ++m) {
            float cx = (gbx[m][0] + fj) * INV_GRID;
            float cy = (gbx[m][1] + fi) * INV_GRID;
            float w = gbx[m][2], h = gbx[m][3];
            gl[m][0] = cx - w * 0.5f; gl[m][1] = cy - h * 0.5f;
            gl[m][2] = cx + w * 0.5f; gl[m][3] = cy + h * 0.5f;
            ga[m] = (gl[m][2] - gl[m][0]) * (gl[m][3] - gl[m][1]);
        }

        // ---- iou(pred k, gt m) and argmax over k (first-max on ties) ----
        int ind[NB];
        #pragma unroll
        for (int m = 0; m < NB; ++m) {
            float iou_km[NB];
            #pragma unroll
            for (int k = 0; k < NB; ++k) {
                float ltx = fmaxf(pl[k][0], gl[m][0]);
                float lty = fmaxf(pl[k][1], gl[m][1]);
                float rbx = fminf(pl[k][2], gl[m][2]);
                float rby = fminf(pl[k][3], gl[m][3]);
                float w = fmaxf(rbx - ltx, 0.0f);
                float h = fmaxf(rby - lty, 0.0f);
                float inter = w * h;
                iou_km[k] = inter / (pa[k] + ga[m] - inter + 1e-7f);
            }
            ind[m] = (iou_km[1] > iou_km[0]) ? 1 : 0;   // jnp.argmax: first max wins
        }

        // gathered[m] = poff[ind[m]]  (size-2 select, keep in registers)
        float gth0[4], gth1[4];
        #pragma unroll
        for (int c = 0; c < 4; ++c) {
            gth0[c] = ind[0] ? po[1][c] : po[0][c];
            gth1[c] = ind[1] ? po[1][c] : po[0][c];
        }

        // same_g: exact elementwise equality of the two gt boxes
        bool same_g = (gbx[0][0] == gbx[1][0]) && (gbx[0][1] == gbx[1][1]) &&
                      (gbx[0][2] == gbx[1][2]) && (gbx[0][3] == gbx[1][3]);
        bool same_ind = (ind[0] == ind[1]);

        float lossA = box_loss(gth0, gbx[0]);
        float lossB = box_loss(po[0], gbx[0]) + box_loss(po[1], gbx[1]);
        float lossC = box_loss(gth0, gbx[0]) + box_loss(gth1, gbx[1]);
        float box_cell = same_g ? lossA : (same_ind ? lossB : lossC);

        float pc0 = pv[IS], pc1 = pv[IS + 1];
        float confA = bce(ind[1] ? pc1 : pc0, 1.0f);
        float confBC = bce(pc0, 1.0f) + bce(pc1, 1.0f);
        float conf_cell = same_g ? confA : confBC;

        acc = 5.0f * box_cell + conf_cell + cls;
    }
    // conf_g < 0: contributes nothing (matches reference masks)

    // ---- block reduction: wave shuffle -> LDS -> one store (or atomic) per block ----
    #pragma unroll
    for (int off = 32; off > 0; off >>= 1) acc += __shfl_down(acc, off, 64);

    const int lane = threadIdx.x & 63;
    const int wid = threadIdx.x >> 6;
    if (lane == 0) ws_red[wid] = acc;
    __syncthreads();
    if (threadIdx.x == 0) {
        float s = ws_red[0] + ws_red[1];
        if (USE_ATOMIC) {
            atomicAdd(partial_or_out, s * INV_BATCH);
        } else {
            partial_or_out[blockIdx.x] = s;   // plain store, no init needed
        }
    }
}

// Single-block final reduction: sums NBLOCKS partials, overwrites poisoned out.
__global__ __launch_bounds__(256) void yolo_reduce_kernel(
        const float* __restrict__ partials, float* __restrict__ out) {
    __shared__ float ws_red[4];
    const int tid = threadIdx.x;
    float acc = 0.0f;
    for (int i = tid; i < NBLOCKS; i += 256) acc += partials[i];
    #pragma unroll
    for (int off = 32; off > 0; off >>= 1) acc += __shfl_down(acc, off, 64);
    const int lane = tid & 63;
    const int wid = tid >> 6;
    if (lane == 0) ws_red[wid] = acc;
    __syncthreads();
    if (tid == 0) {
        out[0] = (ws_red[0] + ws_red[1] + ws_red[2] + ws_red[3]) * INV_BATCH;
    }
}

extern "C" void kernel_launch(void* const* d_in, const int* in_sizes, int n_in,
                              void* d_out, int out_size, void* d_ws, size_t ws_size,
                              hipStream_t stream) {
    const float* p = (const float*)d_in[0];
    const float* g = (const float*)d_in[1];
    float* out = (float*)d_out;

    if (d_ws != nullptr && ws_size >= NBLOCKS * sizeof(float)) {
        // atomic-free path: per-block partials in workspace, 1-block final reduce.
        float* partials = (float*)d_ws;
        yolo_loss_kernel<false><<<NBLOCKS, CPB, 0, stream>>>(p, g, partials);
        yolo_reduce_kernel<<<1, 256, 0, stream>>>(partials, out);
    } else {
        // fallback: memset + atomic accumulation (d_out poisoned 0xAA each call)
        hipMemsetAsync(out, 0, sizeof(float), stream);
        yolo_loss_kernel<true><<<NBLOCKS, CPB, 0, stream>>>(p, g, out);
    }
}